// Round 8
// baseline (106.880 us; speedup 1.0000x reference)
//
#include <hip/hip_runtime.h>
#include <float.h>
#include <math.h>

// B=65536 rows, C=1000 cols, fp32. One wave (64 lanes) per row, persistent
// grid-stride waves with next-row register prefetch (software pipeline).
// R8 = R7 (branch-free clamped prefetch) + EXACTLY ONE change:
// __builtin_amdgcn_sched_barrier(0) after the prefetch issue, pinning the 13
// next-row loads at the loop top (R7 evidence: without a pin the scheduler
// sinks them to the rotate at loop bottom, killing the pipeline, 107us).
// Branch-free body keeps vmcnt counts path-independent -> compiler can emit
// a counted s_waitcnt (wait prev row's loads, keep this row's in flight).
// Per row (X read from HBM exactly once, row lives in 16 VGPRs/lane):
//   pass1: m = max(x), L = dot(x, wL)        (wL cached in 16 VGPRs per wave)
//   pass2: S = sum exp(x-m), W = sum exp(x-m)*x
//   H_hat = W/S - m - log S ;  T = clip(softplus(L + wH*H_hat/lnC + b), EPS)
//   pass3 (regs only): S2 = sum exp((x-m)/T); nll = log S2 - (x_lab - m)/T
// Mean: per-block double partial -> d_ws, tiny final kernel (2048 vals).

static constexpr int   kC4    = 250;   // float4 per row (1000 floats)
static constexpr int   kBlock = 256;   // 4 waves per block
static constexpr int   kGrid  = 2048;  // 8192 waves -> 8 rows/wave at B=65536
static constexpr int   kWavesTotal = kGrid * (kBlock / 64);
static constexpr float kEps   = 1.1920928955078125e-07f;  // FLT_EPSILON
static constexpr float kLogC  = 6.907755279f;             // ln(1000)

__device__ __forceinline__ float wred_max(float v) {
#pragma unroll
  for (int off = 32; off > 0; off >>= 1) v = fmaxf(v, __shfl_xor(v, off, 64));
  return v;
}
__device__ __forceinline__ float wred_sum(float v) {
#pragma unroll
  for (int off = 32; off > 0; off >>= 1) v += __shfl_xor(v, off, 64);
  return v;
}

__device__ __forceinline__ void p1_dot_max(const float4 c, const float4 w,
                                           float& L, float& m) {
  L = fmaf(c.x, w.x, L); L = fmaf(c.y, w.y, L);
  L = fmaf(c.z, w.z, L); L = fmaf(c.w, w.w, L);
  m = fmaxf(m, fmaxf(fmaxf(c.x, c.y), fmaxf(c.z, c.w)));
}
__device__ __forceinline__ void p2_sumexp(const float4 c, const float m,
                                          float& S, float& W) {
  float e;
  e = __expf(c.x - m); S += e; W = fmaf(e, c.x, W);
  e = __expf(c.y - m); S += e; W = fmaf(e, c.y, W);
  e = __expf(c.z - m); S += e; W = fmaf(e, c.z, W);
  e = __expf(c.w - m); S += e; W = fmaf(e, c.w, W);
}
__device__ __forceinline__ void p3_sumexp2(const float4 c, const float rT,
                                           const float nmrT, float& S2) {
  S2 += __expf(fmaf(c.x, rT, nmrT)); S2 += __expf(fmaf(c.y, rT, nmrT));
  S2 += __expf(fmaf(c.z, rT, nmrT)); S2 += __expf(fmaf(c.w, rT, nmrT));
}

#define SENT4 make_float4(-FLT_MAX, -FLT_MAX, -FLT_MAX, -FLT_MAX)

__global__ __launch_bounds__(kBlock) void ats_row_kernel(
    const float* __restrict__ X, const int* __restrict__ labels,
    const float* __restrict__ wL, const float* __restrict__ wH,
    const float* __restrict__ bb, double* __restrict__ partial, int B) {
  const int lane   = threadIdx.x & 63;
  const int wib    = threadIdx.x >> 6;                    // wave in block
  const int wid    = blockIdx.x * (kBlock / 64) + wib;    // global wave id
  const bool tailok = lane < (kC4 - 192);                 // lanes 0..57

  // wL cached once per wave (row-invariant), 16 VGPRs
  const float4* WLr = reinterpret_cast<const float4*>(wL);
  const float4 w0 = WLr[lane];
  const float4 w1 = WLr[64 + lane];
  const float4 w2 = WLr[128 + lane];
  const float4 w3 = tailok ? WLr[192 + lane] : make_float4(0.f, 0.f, 0.f, 0.f);
  const float wH0 = wH[0];
  const float b0  = bb[0];

  double acc = 0.0;

  // ---- prefetch first row (wid < kWavesTotal <= B always)
  int row = wid;
  float4 c0, c1, c2, c3;
  int labc;
  {
    const float4* Xr = reinterpret_cast<const float4*>(X) + (size_t)row * kC4;
    c0 = Xr[lane]; c1 = Xr[64 + lane]; c2 = Xr[128 + lane];
    c3 = tailok ? Xr[192 + lane] : SENT4;
    labc = labels[row];
  }

  for (; row < B; row += kWavesTotal) {
    // ---- UNCONDITIONAL clamped prefetch, PINNED at loop top
    const int nrow = row + kWavesTotal;
    const int prow = (nrow < B) ? nrow : (B - 1);
    float4 n0, n1, n2, n3;
    int labn;
    {
      const float4* Xn = reinterpret_cast<const float4*>(X) + (size_t)prow * kC4;
      n0 = Xn[lane]; n1 = Xn[64 + lane]; n2 = Xn[128 + lane];
      n3 = tailok ? Xn[192 + lane] : SENT4;
      labn = labels[prow];
    }
    // Pin: nothing (esp. the 13 loads above) may be scheduled across this.
    __builtin_amdgcn_sched_barrier(0);

    // ---- pass1: max + dot (sentinel -FLT_MAX never wins max; w3=0 on tail)
    float L = 0.f, m = -FLT_MAX;
    p1_dot_max(c0, w0, L, m); p1_dot_max(c1, w1, L, m);
    p1_dot_max(c2, w2, L, m); p1_dot_max(c3, w3, L, m);
    m = wred_max(m);

    // ---- pass2: S = sum e, W = sum e*x  (exp underflows to 0 on sentinel)
    float S = 0.f, W = 0.f;
    p2_sumexp(c0, m, S, W); p2_sumexp(c1, m, S, W);
    p2_sumexp(c2, m, S, W); p2_sumexp(c3, m, S, W);
    S = wred_sum(S);
    W = wred_sum(W);
    L = wred_sum(L);

    // ---- x[label]: slot/elem are wave-uniform, one shfl broadcast
    const int c4l = labc >> 2;
    const int sl  = c4l >> 6, ln = c4l & 63, el = labc & 3;
    float4 v = (sl == 0) ? c0 : (sl == 1) ? c1 : (sl == 2) ? c2 : c3;
    float cand = (el == 0) ? v.x : (el == 1) ? v.y : (el == 2) ? v.z : v.w;
    const float xl = __shfl(cand, ln, 64);

    // ---- temperature
    const float Hhat = W / S - m - __logf(S);
    const float a    = L + wH0 * (Hhat / kLogC) + b0;
    const float sp   = (a > 0.f) ? (a + log1pf(__expf(-a))) : log1pf(__expf(a));
    const float T    = fmaxf(sp, kEps);
    const float rT   = 1.0f / T;
    const float nmrT = -m * rT;

    // ---- pass3: S2 = sum exp((x-m)/T)  (registers only)
    float S2 = 0.f;
    p3_sumexp2(c0, rT, nmrT, S2); p3_sumexp2(c1, rT, nmrT, S2);
    p3_sumexp2(c2, rT, nmrT, S2); p3_sumexp2(c3, rT, nmrT, S2);
    S2 = wred_sum(S2);

    const float nll = __logf(S2) - fmaf(xl, rT, nmrT);  // logS2 - (xl-m)/T
    acc += (double)nll;

    // ---- rotate pipeline
    c0 = n0; c1 = n1; c2 = n2; c3 = n3; labc = labn;
  }

  // ---- block partial (all lanes hold identical acc; lane 0 per wave writes)
  __shared__ double sacc[kBlock / 64];
  if (lane == 0) sacc[wib] = acc;
  __syncthreads();
  if (threadIdx.x == 0)
    partial[blockIdx.x] = (sacc[0] + sacc[1]) + (sacc[2] + sacc[3]);
}

__global__ __launch_bounds__(256) void ats_final_kernel(
    const double* __restrict__ partial, float* __restrict__ out, int n, int B) {
  __shared__ double sdata[256];
  double a = 0.0;
  for (int i = threadIdx.x; i < n; i += 256) a += partial[i];
  sdata[threadIdx.x] = a;
  __syncthreads();
#pragma unroll
  for (int s = 128; s > 0; s >>= 1) {
    if ((int)threadIdx.x < s) sdata[threadIdx.x] += sdata[threadIdx.x + s];
    __syncthreads();
  }
  if (threadIdx.x == 0) out[0] = (float)(sdata[0] / (double)B);
}

extern "C" void kernel_launch(void* const* d_in, const int* in_sizes, int n_in,
                              void* d_out, int out_size, void* d_ws, size_t ws_size,
                              hipStream_t stream) {
  (void)n_in; (void)out_size; (void)ws_size;
  const float* X   = (const float*)d_in[0];
  const int*   lab = (const int*)d_in[1];
  const float* wL  = (const float*)d_in[2];
  const float* wH  = (const float*)d_in[3];
  const float* bb  = (const float*)d_in[4];
  const int B = in_sizes[1];            // 65536 labels
  double* partial = (double*)d_ws;      // kGrid doubles = 16 KB scratch
  float* out = (float*)d_out;

  ats_row_kernel<<<kGrid, kBlock, 0, stream>>>(X, lab, wL, wH, bb, partial, B);
  ats_final_kernel<<<1, 256, 0, stream>>>(partial, out, kGrid, B);
}

// Round 9
// 65.316 us; speedup vs baseline: 1.6363x; 1.6363x over previous
//
#include <hip/hip_runtime.h>
#include <float.h>
#include <math.h>

// B=65536 rows, C=1000 cols, fp32. One wave (64 lanes) per row, persistent
// grid-stride waves with next-row register prefetch. R9 = R3's exact pipeline
// skeleton (conditional prefetch `if (nrow < B)` — DO NOT TOUCH: R7/R8 showed
// the branch-free clamp regresses 64->107us) + VALU-issue reduction:
//  (1) packed fp32 (v_pk_fma/v_pk_max via __builtin_elementwise_* on float2)
//      halves non-transcendental VALU in pass1/2/3 (~200 -> ~120 slots/row),
//  (2) (S,W,L) butterflies interleaved: serial cross-lane depth 18 -> 6.
// Theory: R3 sits at a VALU/cross-lane throughput ceiling (~4.1 TB/s eff),
// not a memory one; occupancy/scheduling rounds (R4-R8) were all null.

static constexpr int   kC4    = 250;   // float4 per row (1000 floats)
static constexpr int   kBlock = 256;   // 4 waves per block
static constexpr int   kGrid  = 2048;  // 8192 waves -> 8 rows/wave at B=65536
static constexpr int   kWavesTotal = kGrid * (kBlock / 64);
static constexpr float kEps   = 1.1920928955078125e-07f;  // FLT_EPSILON
static constexpr float kLogC  = 6.907755279f;             // ln(1000)

typedef float v2f __attribute__((ext_vector_type(2)));

__device__ __forceinline__ float wred_max(float v) {
#pragma unroll
  for (int off = 32; off > 0; off >>= 1) v = fmaxf(v, __shfl_xor(v, off, 64));
  return v;
}
__device__ __forceinline__ float wred_sum(float v) {
#pragma unroll
  for (int off = 32; off > 0; off >>= 1) v += __shfl_xor(v, off, 64);
  return v;
}
// interleaved butterflies: serial depth 6, ILP-3 across shuffle latency
__device__ __forceinline__ void wred_sum3(float& a, float& b, float& c) {
#pragma unroll
  for (int off = 32; off > 0; off >>= 1) {
    const float ta = __shfl_xor(a, off, 64);
    const float tb = __shfl_xor(b, off, 64);
    const float tc = __shfl_xor(c, off, 64);
    a += ta; b += tb; c += tc;
  }
}

// ---- packed helpers (emit v_pk_fma_f32 / v_pk_max_f32 / v_pk_add_f32) ----
__device__ __forceinline__ void p1_dot_max(const float4 c, const float4 w,
                                           v2f& Lp, v2f& mp) {
  const v2f clo = {c.x, c.y}, chi = {c.z, c.w};
  const v2f wlo = {w.x, w.y}, whi = {w.z, w.w};
  Lp = __builtin_elementwise_fma(clo, wlo, Lp);
  Lp = __builtin_elementwise_fma(chi, whi, Lp);
  mp = __builtin_elementwise_max(mp, __builtin_elementwise_max(clo, chi));
}
__device__ __forceinline__ void p2_sumexp(const float4 c, const float m,
                                          v2f& Sp, v2f& Wp) {
  v2f e, x;
  x.x = c.x; x.y = c.y;
  e.x = __expf(c.x - m); e.y = __expf(c.y - m);
  Sp += e;  Wp = __builtin_elementwise_fma(e, x, Wp);
  x.x = c.z; x.y = c.w;
  e.x = __expf(c.z - m); e.y = __expf(c.w - m);
  Sp += e;  Wp = __builtin_elementwise_fma(e, x, Wp);
}
__device__ __forceinline__ void p3_sumexp2(const float4 c, const v2f rT2,
                                           const v2f nmrT2, v2f& S2p) {
  v2f x, a, e;
  x.x = c.x; x.y = c.y;
  a = __builtin_elementwise_fma(x, rT2, nmrT2);
  e.x = __expf(a.x); e.y = __expf(a.y);
  S2p += e;
  x.x = c.z; x.y = c.w;
  a = __builtin_elementwise_fma(x, rT2, nmrT2);
  e.x = __expf(a.x); e.y = __expf(a.y);
  S2p += e;
}

#define SENT4 make_float4(-FLT_MAX, -FLT_MAX, -FLT_MAX, -FLT_MAX)

__global__ __launch_bounds__(kBlock) void ats_row_kernel(
    const float* __restrict__ X, const int* __restrict__ labels,
    const float* __restrict__ wL, const float* __restrict__ wH,
    const float* __restrict__ bb, double* __restrict__ partial, int B) {
  const int lane   = threadIdx.x & 63;
  const int wib    = threadIdx.x >> 6;                    // wave in block
  const int wid    = blockIdx.x * (kBlock / 64) + wib;    // global wave id
  const bool tailok = lane < (kC4 - 192);                 // lanes 0..57

  // wL cached once per wave (row-invariant), 16 VGPRs
  const float4* WLr = reinterpret_cast<const float4*>(wL);
  const float4 w0 = WLr[lane];
  const float4 w1 = WLr[64 + lane];
  const float4 w2 = WLr[128 + lane];
  const float4 w3 = tailok ? WLr[192 + lane] : make_float4(0.f, 0.f, 0.f, 0.f);
  const float wH0 = wH[0];
  const float b0  = bb[0];

  double acc = 0.0;

  // ---- prefetch first row (wid < kWavesTotal <= B always)
  int row = wid;
  float4 c0, c1, c2, c3;
  int labc;
  {
    const float4* Xr = reinterpret_cast<const float4*>(X) + (size_t)row * kC4;
    c0 = Xr[lane]; c1 = Xr[64 + lane]; c2 = Xr[128 + lane];
    c3 = tailok ? Xr[192 + lane] : SENT4;
    labc = labels[row];
  }

  for (; row < B; row += kWavesTotal) {
    // ---- prefetch next row (CONDITIONAL — exactly as R3; see header)
    const int nrow = row + kWavesTotal;
    float4 n0 = SENT4, n1 = SENT4, n2 = SENT4, n3 = SENT4;
    int labn = 0;
    if (nrow < B) {
      const float4* Xn = reinterpret_cast<const float4*>(X) + (size_t)nrow * kC4;
      n0 = Xn[lane]; n1 = Xn[64 + lane]; n2 = Xn[128 + lane];
      n3 = tailok ? Xn[192 + lane] : SENT4;
      labn = labels[nrow];
    }

    // ---- pass1 (packed): max + dot; sentinel -FLT_MAX never wins, w3=0 tail
    v2f Lp = {0.f, 0.f}, mp = {-FLT_MAX, -FLT_MAX};
    p1_dot_max(c0, w0, Lp, mp); p1_dot_max(c1, w1, Lp, mp);
    p1_dot_max(c2, w2, Lp, mp); p1_dot_max(c3, w3, Lp, mp);
    float L = Lp.x + Lp.y;
    float m = wred_max(fmaxf(mp.x, mp.y));

    // ---- pass2 (packed): S = sum e, W = sum e*x (exp underflow->0 sentinel)
    v2f Sp = {0.f, 0.f}, Wp = {0.f, 0.f};
    p2_sumexp(c0, m, Sp, Wp); p2_sumexp(c1, m, Sp, Wp);
    p2_sumexp(c2, m, Sp, Wp); p2_sumexp(c3, m, Sp, Wp);
    float S = Sp.x + Sp.y, W = Wp.x + Wp.y;
    wred_sum3(S, W, L);

    // ---- x[label]: slot/elem are wave-uniform, one shfl broadcast
    const int c4l = labc >> 2;
    const int sl  = c4l >> 6, ln = c4l & 63, el = labc & 3;
    float4 v = (sl == 0) ? c0 : (sl == 1) ? c1 : (sl == 2) ? c2 : c3;
    float cand = (el == 0) ? v.x : (el == 1) ? v.y : (el == 2) ? v.z : v.w;
    const float xl = __shfl(cand, ln, 64);

    // ---- temperature
    const float Hhat = W / S - m - __logf(S);
    const float a    = L + wH0 * (Hhat / kLogC) + b0;
    const float sp   = (a > 0.f) ? (a + log1pf(__expf(-a))) : log1pf(__expf(a));
    const float T    = fmaxf(sp, kEps);
    const float rT   = 1.0f / T;
    const float nmrT = -m * rT;
    const v2f rT2   = {rT, rT};
    const v2f nmrT2 = {nmrT, nmrT};

    // ---- pass3 (packed): S2 = sum exp((x-m)/T)  (registers only)
    v2f S2p = {0.f, 0.f};
    p3_sumexp2(c0, rT2, nmrT2, S2p); p3_sumexp2(c1, rT2, nmrT2, S2p);
    p3_sumexp2(c2, rT2, nmrT2, S2p); p3_sumexp2(c3, rT2, nmrT2, S2p);
    float S2 = wred_sum(S2p.x + S2p.y);

    const float nll = __logf(S2) - fmaf(xl, rT, nmrT);  // logS2 - (xl-m)/T
    acc += (double)nll;

    // ---- rotate pipeline
    c0 = n0; c1 = n1; c2 = n2; c3 = n3; labc = labn;
  }

  // ---- block partial (all lanes hold identical acc; lane 0 per wave writes)
  __shared__ double sacc[kBlock / 64];
  if (lane == 0) sacc[wib] = acc;
  __syncthreads();
  if (threadIdx.x == 0)
    partial[blockIdx.x] = (sacc[0] + sacc[1]) + (sacc[2] + sacc[3]);
}

__global__ __launch_bounds__(256) void ats_final_kernel(
    const double* __restrict__ partial, float* __restrict__ out, int n, int B) {
  __shared__ double sdata[256];
  double a = 0.0;
  for (int i = threadIdx.x; i < n; i += 256) a += partial[i];
  sdata[threadIdx.x] = a;
  __syncthreads();
#pragma unroll
  for (int s = 128; s > 0; s >>= 1) {
    if ((int)threadIdx.x < s) sdata[threadIdx.x] += sdata[threadIdx.x + s];
    __syncthreads();
  }
  if (threadIdx.x == 0) out[0] = (float)(sdata[0] / (double)B);
}

extern "C" void kernel_launch(void* const* d_in, const int* in_sizes, int n_in,
                              void* d_out, int out_size, void* d_ws, size_t ws_size,
                              hipStream_t stream) {
  (void)n_in; (void)out_size; (void)ws_size;
  const float* X   = (const float*)d_in[0];
  const int*   lab = (const int*)d_in[1];
  const float* wL  = (const float*)d_in[2];
  const float* wH  = (const float*)d_in[3];
  const float* bb  = (const float*)d_in[4];
  const int B = in_sizes[1];            // 65536 labels
  double* partial = (double*)d_ws;      // kGrid doubles = 16 KB scratch
  float* out = (float*)d_out;

  ats_row_kernel<<<kGrid, kBlock, 0, stream>>>(X, lab, wL, wH, bb, partial, B);
  ats_final_kernel<<<1, 256, 0, stream>>>(partial, out, kGrid, B);
}

// Round 10
// 63.342 us; speedup vs baseline: 1.6873x; 1.0312x over previous
//
#include <hip/hip_runtime.h>
#include <float.h>
#include <math.h>

// B=65536 rows, C=1000 cols, fp32. One wave (64 lanes) per row-chunk.
// R10 = R3 verbatim EXCEPT row->wave mapping: wave wid owns 8 CONTIGUOUS rows
// [wid*8, wid*8+8) instead of rows strided by 8192. Per-wave reads become
// sequential 32KB streams (DRAM row-buffer locality) instead of 32MB jumps.
// Tests the hypothesis that scattered 4KB windows cap pure-read at ~4.2TB/s.
// Generic fallback kernel (R3 mapping) retained for B not divisible.
// Per row (X read from HBM exactly once, row lives in 16 VGPRs/lane):
//   pass1: m = max(x), L = dot(x, wL)        (wL cached in 16 VGPRs per wave)
//   pass2: S = sum exp(x-m), W = sum exp(x-m)*x
//   H_hat = W/S - m - log S ;  T = clip(softplus(L + wH*H_hat/lnC + b), EPS)
//   pass3 (regs only): S2 = sum exp((x-m)/T); nll = log S2 - (x_lab - m)/T
// Mean: per-block double partial -> d_ws, tiny final kernel (2048 vals).

static constexpr int   kC4    = 250;   // float4 per row (1000 floats)
static constexpr int   kBlock = 256;   // 4 waves per block
static constexpr int   kGrid  = 2048;  // 8192 waves
static constexpr int   kWavesTotal = kGrid * (kBlock / 64);
static constexpr int   kRPW   = 8;     // rows per wave (contiguous chunk)
static constexpr float kEps   = 1.1920928955078125e-07f;  // FLT_EPSILON
static constexpr float kLogC  = 6.907755279f;             // ln(1000)

__device__ __forceinline__ float wred_max(float v) {
#pragma unroll
  for (int off = 32; off > 0; off >>= 1) v = fmaxf(v, __shfl_xor(v, off, 64));
  return v;
}
__device__ __forceinline__ float wred_sum(float v) {
#pragma unroll
  for (int off = 32; off > 0; off >>= 1) v += __shfl_xor(v, off, 64);
  return v;
}

__device__ __forceinline__ void p1_dot_max(const float4 c, const float4 w,
                                           float& L, float& m) {
  L = fmaf(c.x, w.x, L); L = fmaf(c.y, w.y, L);
  L = fmaf(c.z, w.z, L); L = fmaf(c.w, w.w, L);
  m = fmaxf(m, fmaxf(fmaxf(c.x, c.y), fmaxf(c.z, c.w)));
}
__device__ __forceinline__ void p2_sumexp(const float4 c, const float m,
                                          float& S, float& W) {
  float e;
  e = __expf(c.x - m); S += e; W = fmaf(e, c.x, W);
  e = __expf(c.y - m); S += e; W = fmaf(e, c.y, W);
  e = __expf(c.z - m); S += e; W = fmaf(e, c.z, W);
  e = __expf(c.w - m); S += e; W = fmaf(e, c.w, W);
}
__device__ __forceinline__ void p3_sumexp2(const float4 c, const float rT,
                                           const float nmrT, float& S2) {
  S2 += __expf(fmaf(c.x, rT, nmrT)); S2 += __expf(fmaf(c.y, rT, nmrT));
  S2 += __expf(fmaf(c.z, rT, nmrT)); S2 += __expf(fmaf(c.w, rT, nmrT));
}

#define SENT4 make_float4(-FLT_MAX, -FLT_MAX, -FLT_MAX, -FLT_MAX)

// ---- shared per-row body -------------------------------------------------
__device__ __forceinline__ float row_nll(
    const float4 c0, const float4 c1, const float4 c2, const float4 c3,
    const float4 w0, const float4 w1, const float4 w2, const float4 w3,
    const int labc, const float wH0, const float b0) {
  float L = 0.f, m = -FLT_MAX;
  p1_dot_max(c0, w0, L, m); p1_dot_max(c1, w1, L, m);
  p1_dot_max(c2, w2, L, m); p1_dot_max(c3, w3, L, m);
  m = wred_max(m);

  float S = 0.f, W = 0.f;
  p2_sumexp(c0, m, S, W); p2_sumexp(c1, m, S, W);
  p2_sumexp(c2, m, S, W); p2_sumexp(c3, m, S, W);
  S = wred_sum(S);
  W = wred_sum(W);
  L = wred_sum(L);

  const int c4l = labc >> 2;
  const int sl  = c4l >> 6, ln = c4l & 63, el = labc & 3;
  float4 v = (sl == 0) ? c0 : (sl == 1) ? c1 : (sl == 2) ? c2 : c3;
  float cand = (el == 0) ? v.x : (el == 1) ? v.y : (el == 2) ? v.z : v.w;
  const float xl = __shfl(cand, ln, 64);

  const float Hhat = W / S - m - __logf(S);
  const float a    = L + wH0 * (Hhat / kLogC) + b0;
  const float sp   = (a > 0.f) ? (a + log1pf(__expf(-a))) : log1pf(__expf(a));
  const float T    = fmaxf(sp, kEps);
  const float rT   = 1.0f / T;
  const float nmrT = -m * rT;

  float S2 = 0.f;
  p3_sumexp2(c0, rT, nmrT, S2); p3_sumexp2(c1, rT, nmrT, S2);
  p3_sumexp2(c2, rT, nmrT, S2); p3_sumexp2(c3, rT, nmrT, S2);
  S2 = wred_sum(S2);

  return __logf(S2) - fmaf(xl, rT, nmrT);  // logS2 - (xl-m)/T
}

// ---- specialized: B == kWavesTotal * kRPW, contiguous chunks -------------
__global__ __launch_bounds__(kBlock) void ats_row_kernel_c8(
    const float* __restrict__ X, const int* __restrict__ labels,
    const float* __restrict__ wL, const float* __restrict__ wH,
    const float* __restrict__ bb, double* __restrict__ partial) {
  const int lane   = threadIdx.x & 63;
  const int wib    = threadIdx.x >> 6;
  const int wid    = blockIdx.x * (kBlock / 64) + wib;
  const bool tailok = lane < (kC4 - 192);

  const float4* WLr = reinterpret_cast<const float4*>(wL);
  const float4 w0 = WLr[lane];
  const float4 w1 = WLr[64 + lane];
  const float4 w2 = WLr[128 + lane];
  const float4 w3 = tailok ? WLr[192 + lane] : make_float4(0.f, 0.f, 0.f, 0.f);
  const float wH0 = wH[0];
  const float b0  = bb[0];

  double acc = 0.0;
  const int base = wid * kRPW;

  float4 c0, c1, c2, c3;
  int labc;
  {
    const float4* Xr = reinterpret_cast<const float4*>(X) + (size_t)base * kC4;
    c0 = Xr[lane]; c1 = Xr[64 + lane]; c2 = Xr[128 + lane];
    c3 = tailok ? Xr[192 + lane] : SENT4;
    labc = labels[base];
  }

  for (int i = 0; i < kRPW; ++i) {
    // prefetch next (ADJACENT) row — conditional exactly like R3
    float4 n0 = SENT4, n1 = SENT4, n2 = SENT4, n3 = SENT4;
    int labn = 0;
    if (i + 1 < kRPW) {
      const float4* Xn =
          reinterpret_cast<const float4*>(X) + (size_t)(base + i + 1) * kC4;
      n0 = Xn[lane]; n1 = Xn[64 + lane]; n2 = Xn[128 + lane];
      n3 = tailok ? Xn[192 + lane] : SENT4;
      labn = labels[base + i + 1];
    }

    acc += (double)row_nll(c0, c1, c2, c3, w0, w1, w2, w3, labc, wH0, b0);

    c0 = n0; c1 = n1; c2 = n2; c3 = n3; labc = labn;
  }

  __shared__ double sacc[kBlock / 64];
  if (lane == 0) sacc[wib] = acc;
  __syncthreads();
  if (threadIdx.x == 0)
    partial[blockIdx.x] = (sacc[0] + sacc[1]) + (sacc[2] + sacc[3]);
}

// ---- generic fallback: R3 mapping (grid-stride by kWavesTotal) -----------
__global__ __launch_bounds__(kBlock) void ats_row_kernel_gen(
    const float* __restrict__ X, const int* __restrict__ labels,
    const float* __restrict__ wL, const float* __restrict__ wH,
    const float* __restrict__ bb, double* __restrict__ partial, int B) {
  const int lane   = threadIdx.x & 63;
  const int wib    = threadIdx.x >> 6;
  const int wid    = blockIdx.x * (kBlock / 64) + wib;
  const bool tailok = lane < (kC4 - 192);

  const float4* WLr = reinterpret_cast<const float4*>(wL);
  const float4 w0 = WLr[lane];
  const float4 w1 = WLr[64 + lane];
  const float4 w2 = WLr[128 + lane];
  const float4 w3 = tailok ? WLr[192 + lane] : make_float4(0.f, 0.f, 0.f, 0.f);
  const float wH0 = wH[0];
  const float b0  = bb[0];

  double acc = 0.0;
  int row = wid;
  float4 c0, c1, c2, c3;
  int labc = 0;
  if (row < B) {
    const float4* Xr = reinterpret_cast<const float4*>(X) + (size_t)row * kC4;
    c0 = Xr[lane]; c1 = Xr[64 + lane]; c2 = Xr[128 + lane];
    c3 = tailok ? Xr[192 + lane] : SENT4;
    labc = labels[row];
  }
  for (; row < B; row += kWavesTotal) {
    const int nrow = row + kWavesTotal;
    float4 n0 = SENT4, n1 = SENT4, n2 = SENT4, n3 = SENT4;
    int labn = 0;
    if (nrow < B) {
      const float4* Xn = reinterpret_cast<const float4*>(X) + (size_t)nrow * kC4;
      n0 = Xn[lane]; n1 = Xn[64 + lane]; n2 = Xn[128 + lane];
      n3 = tailok ? Xn[192 + lane] : SENT4;
      labn = labels[nrow];
    }
    acc += (double)row_nll(c0, c1, c2, c3, w0, w1, w2, w3, labc, wH0, b0);
    c0 = n0; c1 = n1; c2 = n2; c3 = n3; labc = labn;
  }
  __shared__ double sacc[kBlock / 64];
  if (lane == 0) sacc[wib] = acc;
  __syncthreads();
  if (threadIdx.x == 0)
    partial[blockIdx.x] = (sacc[0] + sacc[1]) + (sacc[2] + sacc[3]);
}

__global__ __launch_bounds__(256) void ats_final_kernel(
    const double* __restrict__ partial, float* __restrict__ out, int n, int B) {
  __shared__ double sdata[256];
  double a = 0.0;
  for (int i = threadIdx.x; i < n; i += 256) a += partial[i];
  sdata[threadIdx.x] = a;
  __syncthreads();
#pragma unroll
  for (int s = 128; s > 0; s >>= 1) {
    if ((int)threadIdx.x < s) sdata[threadIdx.x] += sdata[threadIdx.x + s];
    __syncthreads();
  }
  if (threadIdx.x == 0) out[0] = (float)(sdata[0] / (double)B);
}

extern "C" void kernel_launch(void* const* d_in, const int* in_sizes, int n_in,
                              void* d_out, int out_size, void* d_ws, size_t ws_size,
                              hipStream_t stream) {
  (void)n_in; (void)out_size; (void)ws_size;
  const float* X   = (const float*)d_in[0];
  const int*   lab = (const int*)d_in[1];
  const float* wL  = (const float*)d_in[2];
  const float* wH  = (const float*)d_in[3];
  const float* bb  = (const float*)d_in[4];
  const int B = in_sizes[1];            // 65536 labels
  double* partial = (double*)d_ws;      // kGrid doubles = 16 KB scratch
  float* out = (float*)d_out;

  if (B == kWavesTotal * kRPW) {
    ats_row_kernel_c8<<<kGrid, kBlock, 0, stream>>>(X, lab, wL, wH, bb, partial);
  } else {
    ats_row_kernel_gen<<<kGrid, kBlock, 0, stream>>>(X, lab, wL, wH, bb,
                                                     partial, B);
  }
  ats_final_kernel<<<1, 256, 0, stream>>>(partial, out, kGrid, B);
}